// Round 11
// baseline (809.249 us; speedup 1.0000x reference)
//
#include <hip/hip_runtime.h>
#include <hip/hip_bf16.h>
#include <hip/hip_cooperative_groups.h>
#include <math.h>

// FraudGNN on MI355X — single persistent cooperative kernel.
// Phases (grid.sync between): count+x->fp8 | scatter(self-offs) | per-bucket
// CSR | agg1 (fp8 gather-mean) | dense MFMA (H1->G fp8, S2 bf16; 64-row tiles)
// | agg2fc (fp8 gather + FC + sigmoid). Rationale: measured ~20us per kernel
// boundary across R2-R10; 6 kernels -> 1 removes ~100us. Aggs ride the
// per-XCD L2-miss line-service ceiling (~1 TB/s) at ~23% above compulsory.

namespace cg = cooperative_groups;

#define IN_C 64
#define HID 128
#define HID2 64
#define LDA 136     // LDS row stride for MFMA tiles
#define NBSHIFT 9   // 512 nodes per bucket
#define BR 512
#define P1B 256     // partition chunks
#define MAXG 768    // target grid (3 blocks/CU)

typedef short short8 __attribute__((ext_vector_type(8)));
typedef float f32x4 __attribute__((ext_vector_type(4)));
typedef float f32x2 __attribute__((ext_vector_type(2)));

__device__ inline unsigned short bfbits(float f) {
    __hip_bfloat16 h = __float2bfloat16(f);
    return *reinterpret_cast<unsigned short*>(&h);
}
__device__ inline float bflo(unsigned u) { return __uint_as_float(u << 16); }
__device__ inline float bfhi(unsigned u) { return __uint_as_float(u & 0xffff0000u); }
__device__ inline unsigned bfpack(float a, float b) {
    return ((unsigned)bfbits(b) << 16) | (unsigned)bfbits(a);
}
__device__ inline unsigned char f_to_fp8(float v) {
    return (unsigned char)(__builtin_amdgcn_cvt_pk_fp8_f32(v, v, 0, false) & 0xff);
}

__global__ __launch_bounds__(256, 3) void mega_kernel(
    const int* __restrict__ ei, const float4* __restrict__ x4,
    const float* __restrict__ x,
    unsigned* __restrict__ xf8, int* __restrict__ cnt,
    int* __restrict__ bucket_base, int* __restrict__ row_ptr,
    int* __restrict__ part, int* __restrict__ srcs,
    unsigned* __restrict__ M1u, unsigned* __restrict__ G8,
    unsigned* __restrict__ S2u,
    const float* __restrict__ W1l, const float* __restrict__ b1,
    const float* __restrict__ W1r, const float* __restrict__ W2l,
    const float* __restrict__ W2r, const float* __restrict__ b2,
    const float* __restrict__ Wfc, const float* __restrict__ bfc,
    float* __restrict__ out, int N, int E, int EPB, int NBUCK)
{
    __shared__ __align__(16) char smem[52224];
    cg::grid_group grid = cg::this_grid();
    int t = threadIdx.x;
    int G = gridDim.x;
    int lane = t & 63, w = t >> 6;

    // ---------- Phase A: per-chunk bucket histogram + x -> fp8 ----------
    {
        int* hist = (int*)smem;
        for (int chunk = blockIdx.x; chunk < P1B; chunk += G) {
            hist[t] = 0;
            __syncthreads();
            int e0 = chunk * EPB, e1 = min(e0 + EPB, E);
            for (int e = e0 + t; e < e1; e += 256)
                atomicAdd(&hist[ei[E + e] >> NBSHIFT], 1);
            __syncthreads();
            if (t < NBUCK) cnt[chunk * NBUCK + t] = hist[t];
            __syncthreads();
        }
        int n4 = N * 16;
        for (int i = blockIdx.x * 256 + t; i < n4; i += G * 256) {
            float4 f = x4[i];
            int lo = __builtin_amdgcn_cvt_pk_fp8_f32(f.x, f.y, 0, false);
            xf8[i] = (unsigned)__builtin_amdgcn_cvt_pk_fp8_f32(f.z, f.w, lo, true);
        }
    }
    grid.sync();

    // ---------- Phase B: scatter with self-computed offsets ----------
    {
        int* tot  = (int*)smem;
        int* lofs = (int*)smem + 256;
        int* wred = (int*)smem + 512;
        for (int chunk = blockIdx.x; chunk < P1B; chunk += G) {
            int pre = 0, total = 0;
            if (t < NBUCK) {
                for (int jj = 0; jj < P1B; ++jj) {
                    int c = cnt[jj * NBUCK + t];
                    total += c;
                    if (jj < chunk) pre += c;
                }
            }
            tot[t] = (t < NBUCK) ? total : 0;
            __syncthreads();
            int v = tot[t];
            int xx = v;
            for (int off = 1; off < 64; off <<= 1) {
                int u = __shfl_up(xx, off);
                if (lane >= off) xx += u;
            }
            if (lane == 63) wred[w] = xx;
            __syncthreads();
            int add = 0;
            for (int k = 0; k < w; ++k) add += wred[k];
            int bb = xx + add - v;
            lofs[t] = bb + pre;
            if (chunk == 0) {
                if (t < NBUCK) bucket_base[t] = bb;
                if (t == 0) { bucket_base[NBUCK] = E; row_ptr[N] = E; }
            }
            __syncthreads();
            int e0 = chunk * EPB, e1 = min(e0 + EPB, E);
            for (int e = e0 + t; e < e1; e += 256) {
                int s = ei[e], d = ei[E + e];
                int b = d >> NBSHIFT;
                int p = atomicAdd(&lofs[b], 1);
                part[p] = (s << NBSHIFT) | (d & (BR - 1));
            }
            __syncthreads();
        }
    }
    grid.sync();

    // ---------- Phase C: per-bucket local CSR ----------
    {
        int* ncnt  = (int*)smem;
        int* nofs  = (int*)smem + BR;
        int* nfill = (int*)smem + 2 * BR;
        int* wred  = (int*)smem + 3 * BR;
        for (int b = blockIdx.x; b < NBUCK; b += G) {
            int node0 = b << NBSHIFT;
            int nn = min(BR, N - node0);
            int gb0 = bucket_base[b], gb1 = bucket_base[b + 1];
            ncnt[t] = 0; ncnt[t + 256] = 0;
            __syncthreads();
            for (int i = gb0 + t; i < gb1; i += 256)
                atomicAdd(&ncnt[part[i] & (BR - 1)], 1);
            __syncthreads();
            int c0 = ncnt[2 * t], c1 = ncnt[2 * t + 1];
            int v = c0 + c1;
            int xx = v;
            for (int off = 1; off < 64; off <<= 1) {
                int u = __shfl_up(xx, off);
                if (lane >= off) xx += u;
            }
            if (lane == 63) wred[w] = xx;
            __syncthreads();
            int add = 0;
            for (int k = 0; k < w; ++k) add += wred[k];
            int exc = xx + add - v;
            nofs[2 * t] = exc;          nofs[2 * t + 1] = exc + c0;
            nfill[2 * t] = exc;         nfill[2 * t + 1] = exc + c0;
            __syncthreads();
            for (int i = t; i < nn; i += 256) row_ptr[node0 + i] = gb0 + nofs[i];
            for (int i = gb0 + t; i < gb1; i += 256) {
                int p = part[i];
                int pos = atomicAdd(&nfill[p & (BR - 1)], 1);
                srcs[gb0 + pos] = ((unsigned)p) >> NBSHIFT;
            }
            __syncthreads();
        }
    }
    grid.sync();

    // ---------- Phase D: gather-mean of x(fp8) -> M1 (bf16) ----------
    {
        int ql = lane & 15, quarter = lane >> 4;
        for (int node = blockIdx.x * 4 + w; node < N; node += G * 4) {
            int s0 = row_ptr[node], s1 = row_ptr[node + 1];
            float a0 = 0.f, a1 = 0.f, a2 = 0.f, a3 = 0.f;
            for (int e = s0; e < s1; e += 16) {
#pragma unroll
                for (int k = 0; k < 4; ++k) {
                    int ek = e + quarter + 4 * k;
                    bool valid = ek < s1;
                    int src = srcs[valid ? ek : 0];
                    unsigned u = xf8[(size_t)src * 16 + ql];
                    if (valid) {
                        f32x2 lo = __builtin_amdgcn_cvt_pk_f32_fp8((int)u, false);
                        f32x2 hi = __builtin_amdgcn_cvt_pk_f32_fp8((int)u, true);
                        a0 += lo[0]; a1 += lo[1]; a2 += hi[0]; a3 += hi[1];
                    }
                }
            }
            a0 += __shfl_xor(a0, 16); a0 += __shfl_xor(a0, 32);
            a1 += __shfl_xor(a1, 16); a1 += __shfl_xor(a1, 32);
            a2 += __shfl_xor(a2, 16); a2 += __shfl_xor(a2, 32);
            a3 += __shfl_xor(a3, 16); a3 += __shfl_xor(a3, 32);
            int deg = s1 - s0;
            float scale = deg > 0 ? 1.f / (float)deg : 0.f;
            if (quarter == 0) {
                uint2 p;
                p.x = bfpack(a0 * scale, a1 * scale);
                p.y = bfpack(a2 * scale, a3 * scale);
                ((uint2*)M1u)[(size_t)node * 16 + ql] = p;
            }
        }
    }
    grid.sync();

    // ---------- Phase E: dense (64-row tiles): H1 -> G(fp8), S2(bf16) -------
    {
        unsigned short* sA = (unsigned short*)smem;             // 64 x LDA
        unsigned short* sB = (unsigned short*)(smem + 64 * LDA * 2); // 128 x LDA
        const unsigned short* M1s = (const unsigned short*)M1u;
        int ntiles = (N + 63) >> 6;
        int mr = lane & 15, q = lane >> 4;
        const f32x4 zero = {0.f, 0.f, 0.f, 0.f};
        for (int tile = blockIdx.x; tile < ntiles; tile += G) {
            int base = tile * 64;
            // stage B1^T and A
            for (int i = t; i < 128 * 128; i += 256) {
                int k = i >> 7, n = i & 127;
                float wv = (k < 64) ? W1l[k * HID + n] : W1r[(k - 64) * HID + n];
                sB[n * LDA + k] = bfbits(wv);
            }
            for (int i = t; i < 64 * 64; i += 256) {
                int r = i >> 6, c = i & 63;
                int node = min(base + r, N - 1);
                sA[r * LDA + c] = M1s[(size_t)node * 64 + c];
                sA[r * LDA + 64 + c] = bfbits(x[(size_t)node * 64 + c]);
            }
            __syncthreads();

            int m0 = w * 16;
            f32x4 acc[8];
#pragma unroll
            for (int nt = 0; nt < 8; ++nt) acc[nt] = zero;
#pragma unroll
            for (int kt = 0; kt < 4; ++kt) {
                short8 a = *reinterpret_cast<const short8*>(&sA[(m0 + mr) * LDA + kt * 32 + q * 8]);
#pragma unroll
                for (int nt = 0; nt < 8; ++nt) {
                    short8 b = *reinterpret_cast<const short8*>(&sB[(nt * 16 + mr) * LDA + kt * 32 + q * 8]);
                    acc[nt] = __builtin_amdgcn_mfma_f32_16x16x32_bf16(a, b, acc[nt], 0, 0, 0);
                }
            }
            __syncthreads();
            // H1 = relu(acc + b1) -> sA ; stage B2^T -> sB
#pragma unroll
            for (int nt = 0; nt < 8; ++nt)
#pragma unroll
                for (int j = 0; j < 4; ++j) {
                    int row = m0 + q * 4 + j;
                    int col = nt * 16 + mr;
                    float v = acc[nt][j] + b1[col];
                    sA[row * LDA + col] = bfbits(fmaxf(v, 0.f));
                }
            for (int i = t; i < 128 * 128; i += 256) {
                int c = i >> 7, n = i & 127;
                float wv = (n < 64) ? W2l[c * HID2 + n] : W2r[c * HID2 + (n - 64)];
                sB[n * LDA + c] = bfbits(wv);
            }
            __syncthreads();

            f32x4 acc2[8];
#pragma unroll
            for (int nt = 0; nt < 8; ++nt) acc2[nt] = zero;
#pragma unroll
            for (int kt = 0; kt < 4; ++kt) {
                short8 a = *reinterpret_cast<const short8*>(&sA[(m0 + mr) * LDA + kt * 32 + q * 8]);
#pragma unroll
                for (int nt = 0; nt < 8; ++nt) {
                    short8 b = *reinterpret_cast<const short8*>(&sB[(nt * 16 + mr) * LDA + kt * 32 + q * 8]);
                    acc2[nt] = __builtin_amdgcn_mfma_f32_16x16x32_bf16(a, b, acc2[nt], 0, 0, 0);
                }
            }
            __syncthreads(); // all stage-2 LDS reads done; reuse sA/sB as staging

            unsigned char* sG = (unsigned char*)sA;      // [64][64] fp8
            unsigned short* sS = (unsigned short*)sB;    // [64][64] bf16
#pragma unroll
            for (int nt = 0; nt < 8; ++nt)
#pragma unroll
                for (int j = 0; j < 4; ++j) {
                    int row = m0 + q * 4 + j;
                    int col = nt * 16 + mr;
                    float v = acc2[nt][j];
                    if (col < 64) sG[row * 64 + col] = f_to_fp8(v);
                    else          sS[row * 64 + (col - 64)] = bfbits(v);
                }
            __syncthreads();
            const unsigned* sGu = (const unsigned*)sG;
            for (int i = t; i < 64 * 16; i += 256) {
                int r = i >> 4, node = base + r;
                if (node < N) G8[(size_t)node * 16 + (i & 15)] = sGu[i];
            }
            const unsigned* sSu = (const unsigned*)sS;
            for (int i = t; i < 64 * 32; i += 256) {
                int r = i >> 5, node = base + r;
                if (node < N) S2u[(size_t)node * 32 + (i & 31)] = sSu[i];
            }
            __syncthreads();
        }
    }
    grid.sync();

    // ---------- Phase F: gather-mean of G(fp8) + FC + sigmoid ----------
    {
        int ql = lane & 15, quarter = lane >> 4;
        for (int node = blockIdx.x * 4 + w; node < N; node += G * 4) {
            int s0 = row_ptr[node], s1 = row_ptr[node + 1];
            float a0 = 0.f, a1 = 0.f, a2 = 0.f, a3 = 0.f;
            for (int e = s0; e < s1; e += 16) {
#pragma unroll
                for (int k = 0; k < 4; ++k) {
                    int ek = e + quarter + 4 * k;
                    bool valid = ek < s1;
                    int src = srcs[valid ? ek : 0];
                    unsigned u = G8[(size_t)src * 16 + ql];
                    if (valid) {
                        f32x2 lo = __builtin_amdgcn_cvt_pk_f32_fp8((int)u, false);
                        f32x2 hi = __builtin_amdgcn_cvt_pk_f32_fp8((int)u, true);
                        a0 += lo[0]; a1 += lo[1]; a2 += hi[0]; a3 += hi[1];
                    }
                }
            }
            a0 += __shfl_xor(a0, 16); a0 += __shfl_xor(a0, 32);
            a1 += __shfl_xor(a1, 16); a1 += __shfl_xor(a1, 32);
            a2 += __shfl_xor(a2, 16); a2 += __shfl_xor(a2, 32);
            a3 += __shfl_xor(a3, 16); a3 += __shfl_xor(a3, 32);
            int deg = s1 - s0;
            float scale = deg > 0 ? 1.f / (float)deg : 0.f;
            uint2 s2p = ((const uint2*)(S2u + (size_t)node * 32))[ql];
            float4 b4 = ((const float4*)b2)[ql];
            float4 w4 = ((const float4*)Wfc)[ql];
            float z = fmaxf(a0 * scale + bflo(s2p.x) + b4.x, 0.f) * w4.x
                    + fmaxf(a1 * scale + bfhi(s2p.x) + b4.y, 0.f) * w4.y
                    + fmaxf(a2 * scale + bflo(s2p.y) + b4.z, 0.f) * w4.z
                    + fmaxf(a3 * scale + bfhi(s2p.y) + b4.w, 0.f) * w4.w;
            z += __shfl_xor(z, 1); z += __shfl_xor(z, 2);
            z += __shfl_xor(z, 4); z += __shfl_xor(z, 8);
            if (lane == 0) out[node] = 1.f / (1.f + __expf(-(z + bfc[0])));
        }
    }
}

// ---------------- launch ----------------
static inline size_t align_up(size_t v, size_t a) { return (v + a - 1) & ~(a - 1); }

extern "C" void kernel_launch(void* const* d_in, const int* in_sizes, int n_in,
                              void* d_out, int out_size, void* d_ws, size_t ws_size,
                              hipStream_t stream) {
    const float* x   = (const float*)d_in[0];
    const int*   ei  = (const int*)d_in[1];
    const float* W1l = (const float*)d_in[2];
    const float* b1  = (const float*)d_in[3];
    const float* W1r = (const float*)d_in[4];
    const float* W2l = (const float*)d_in[5];
    const float* b2  = (const float*)d_in[6];
    const float* W2r = (const float*)d_in[7];
    const float* Wfc = (const float*)d_in[8];
    const float* bfc = (const float*)d_in[9];
    float* out = (float*)d_out;

    int N = in_sizes[0] / IN_C;   // 100000
    int E = in_sizes[1] / 2;      // 1600000
    int NBUCK = (N + BR - 1) / BR;        // 196
    int EPB = (E + P1B - 1) / P1B;        // 6250

    char* ws = (char*)d_ws;
    size_t o = 0;
    int* row_ptr  = (int*)(ws + o); o = align_up(o + (size_t)(N + 1) * 4, 256);
    int* srcs     = (int*)(ws + o); o = align_up(o + (size_t)E * 4, 256);
    int* cnt      = (int*)(ws + o); o = align_up(o + (size_t)P1B * 256 * 4, 256);
    int* bb       = (int*)(ws + o); o = align_up(o + 257 * 4, 256);
    // part (E*4 = 6.4 MB) aliases S2u (N*128 B = 12.8 MB): part dead before
    // phase E writes S2u.
    size_t part_off = o;
    size_t sz1 = (size_t)E * 4, sz2 = (size_t)N * 128;
    o = align_up(part_off + (sz1 > sz2 ? sz1 : sz2), 256);
    int* part = (int*)(ws + part_off);
    unsigned* S2u = (unsigned*)(ws + part_off);
    unsigned* xf8 = (unsigned*)(ws + o); o = align_up(o + (size_t)N * 16 * 4, 256);
    unsigned* M1u = (unsigned*)(ws + o); o = align_up(o + (size_t)N * 32 * 4, 256);
    unsigned* G8  = (unsigned*)(ws + o); o = align_up(o + (size_t)N * 16 * 4, 256);

    int maxb = 0;
    hipOccupancyMaxActiveBlocksPerMultiprocessor(&maxb, mega_kernel, 256, 0);
    if (maxb < 1) maxb = 1;
    int G = maxb * 256;
    if (G > MAXG) G = MAXG;

    const float4* x4 = (const float4*)x;
    void* args[] = {
        (void*)&ei, (void*)&x4, (void*)&x, (void*)&xf8, (void*)&cnt,
        (void*)&bb, (void*)&row_ptr, (void*)&part, (void*)&srcs,
        (void*)&M1u, (void*)&G8, (void*)&S2u,
        (void*)&W1l, (void*)&b1, (void*)&W1r, (void*)&W2l, (void*)&W2r,
        (void*)&b2, (void*)&Wfc, (void*)&bfc, (void*)&out,
        (void*)&N, (void*)&E, (void*)&EPB, (void*)&NBUCK
    };
    hipLaunchCooperativeKernel((void*)mega_kernel, dim3(G), dim3(256),
                               args, 0, stream);
}

// Round 12
// 381.636 us; speedup vs baseline: 2.1205x; 2.1205x over previous
//
#include <hip/hip_runtime.h>
#include <hip/hip_bf16.h>
#include <math.h>

// FraudGNN on MI355X. Counting-sort CSR (count -> scatter[self-offs] -> csr),
// then FUSED aggdense: per 64-node tile, quarter-wave fp8 gather-mean written
// straight into the LDS MFMA A-tile (no M1 global round-trip), two MFMA
// stages (H1 -> G fp8, S2 bf16), then agg2fc (fp8 gather + FC + sigmoid).
// 5 kernels. NOT a cooperative mega-kernel: R11 showed grid.sync costs more
// than a kernel boundary (cross-XCD L2 writeback + min-occupancy coupling).

#define IN_C 64
#define HID 128
#define HID2 64
#define LDA 136     // LDS row stride for MFMA tiles
#define NBSHIFT 9   // 512 nodes per bucket
#define BR 512
#define P1B 256     // partition chunks (needs NBUCK <= 256: N <= 131072)

typedef short short8 __attribute__((ext_vector_type(8)));
typedef float f32x4 __attribute__((ext_vector_type(4)));
typedef float f32x2 __attribute__((ext_vector_type(2)));

__device__ inline unsigned short bfbits(float f) {
    __hip_bfloat16 h = __float2bfloat16(f);
    return *reinterpret_cast<unsigned short*>(&h);
}
__device__ inline float bflo(unsigned u) { return __uint_as_float(u << 16); }
__device__ inline float bfhi(unsigned u) { return __uint_as_float(u & 0xffff0000u); }
__device__ inline unsigned bfpack(float a, float b) {
    return ((unsigned)bfbits(b) << 16) | (unsigned)bfbits(a);
}
__device__ inline unsigned char f_to_fp8(float v) {
    return (unsigned char)(__builtin_amdgcn_cvt_pk_fp8_f32(v, v, 0, false) & 0xff);
}

// ---------------- k1: per-chunk bucket histogram + x->fp8 ----------------
__global__ __launch_bounds__(256) void count_kernel(
    const int* __restrict__ ei, int* __restrict__ cnt,
    const float4* __restrict__ x4, unsigned* __restrict__ xf8,
    int n4, int E, int EPB, int NBUCK)
{
    __shared__ int hist[256];
    int t = threadIdx.x, j = blockIdx.x;
    hist[t] = 0;
    __syncthreads();
    int e0 = j * EPB, e1 = min(e0 + EPB, E);
    for (int e = e0 + t; e < e1; e += 256)
        atomicAdd(&hist[ei[E + e] >> NBSHIFT], 1);
    for (int i = j * 256 + t; i < n4; i += P1B * 256) {
        float4 f = x4[i];
        int lo = __builtin_amdgcn_cvt_pk_fp8_f32(f.x, f.y, 0, false);
        xf8[i] = (unsigned)__builtin_amdgcn_cvt_pk_fp8_f32(f.z, f.w, lo, true);
    }
    __syncthreads();
    if (t < NBUCK) cnt[j * NBUCK + t] = hist[t];
}

// ---------------- k2: scatter with self-computed offsets ----------------
__global__ __launch_bounds__(256) void scatter_kernel(
    const int* __restrict__ ei, const int* __restrict__ cnt,
    int* __restrict__ bucket_base, int* __restrict__ row_ptr,
    int* __restrict__ part, int N, int E, int EPB, int NBUCK)
{
    __shared__ int tot[256];
    __shared__ int lofs[256];
    __shared__ int wred[4];
    int t = threadIdx.x, j = blockIdx.x;
    int lane = t & 63, w = t >> 6;
    int pre = 0, total = 0;
    if (t < NBUCK) {
        for (int jj = 0; jj < P1B; ++jj) {       // coalesced across t per jj
            int c = cnt[jj * NBUCK + t];
            total += c;
            if (jj < j) pre += c;
        }
    }
    tot[t] = (t < NBUCK) ? total : 0;
    __syncthreads();
    int v = tot[t];
    int x = v;
    for (int off = 1; off < 64; off <<= 1) {
        int u = __shfl_up(x, off);
        if (lane >= off) x += u;
    }
    if (lane == 63) wred[w] = x;
    __syncthreads();
    int add = 0;
    for (int k = 0; k < w; ++k) add += wred[k];
    int bb = x + add - v;
    lofs[t] = bb + pre;
    if (j == 0) {
        if (t < NBUCK) bucket_base[t] = bb;
        if (t == 0) { bucket_base[NBUCK] = E; row_ptr[N] = E; }
    }
    __syncthreads();
    int e0 = j * EPB, e1 = min(e0 + EPB, E);
    for (int e = e0 + t; e < e1; e += 256) {
        int s = ei[e], d = ei[E + e];
        int b = d >> NBSHIFT;
        int p = atomicAdd(&lofs[b], 1);
        part[p] = (s << NBSHIFT) | (d & (BR - 1));
    }
}

// ---------------- k3: per-bucket local CSR ----------------
__global__ __launch_bounds__(256) void csr_kernel(
    const int* __restrict__ part, const int* __restrict__ bucket_base,
    int* __restrict__ row_ptr, int* __restrict__ srcs, int N)
{
    __shared__ int ncnt[BR];
    __shared__ int nofs[BR];
    __shared__ int nfill[BR];
    __shared__ int wred[4];
    int b = blockIdx.x;
    int t = threadIdx.x, lane = t & 63, w = t >> 6;
    int node0 = b << NBSHIFT;
    int nn = min(BR, N - node0);
    int gb0 = bucket_base[b], gb1 = bucket_base[b + 1];
    ncnt[t] = 0; ncnt[t + 256] = 0;
    __syncthreads();
    for (int i = gb0 + t; i < gb1; i += 256)
        atomicAdd(&ncnt[part[i] & (BR - 1)], 1);
    __syncthreads();
    int c0 = ncnt[2 * t], c1 = ncnt[2 * t + 1];
    int v = c0 + c1;
    int x = v;
    for (int off = 1; off < 64; off <<= 1) {
        int u = __shfl_up(x, off);
        if (lane >= off) x += u;
    }
    if (lane == 63) wred[w] = x;
    __syncthreads();
    int add = 0;
    for (int k = 0; k < w; ++k) add += wred[k];
    int exc = x + add - v;
    nofs[2 * t] = exc;          nofs[2 * t + 1] = exc + c0;
    nfill[2 * t] = exc;         nfill[2 * t + 1] = exc + c0;
    __syncthreads();
    for (int i = t; i < nn; i += 256) row_ptr[node0 + i] = gb0 + nofs[i];
    for (int i = gb0 + t; i < gb1; i += 256) {
        int p = part[i];
        int pos = atomicAdd(&nfill[p & (BR - 1)], 1);
        srcs[gb0 + pos] = ((unsigned)p) >> NBSHIFT;
    }
}

// ---------------- k4: FUSED agg1 + dense ----------------
// Block = 64-node tile. Wave w aggregates nodes w*16..w*16+15 (quarter-wave
// fp8 gather, bf16 mean written straight into sA), then the block runs
// H1 = relu([M1|xb] @ [W1l;W1r] + b1), G = H1@W2l (fp8), S2 = H1@W2r (bf16).
__global__ __launch_bounds__(256) void aggdense_kernel(
    const unsigned* __restrict__ xf8, const int* __restrict__ row_ptr,
    const int* __restrict__ srcs, const float* __restrict__ x,
    const float* __restrict__ W1l, const float* __restrict__ b1,
    const float* __restrict__ W1r, const float* __restrict__ W2l,
    const float* __restrict__ W2r, unsigned* __restrict__ G8,
    unsigned* __restrict__ S2u, int N)
{
    __shared__ unsigned short sA[64 * LDA];    // [M1 | xb] tile, then H1
    __shared__ unsigned short sB[128 * LDA];   // W1^T, then W2^T
    int t = threadIdx.x;
    int base = blockIdx.x * 64;
    int lane = t & 63, w = t >> 6;
    int ql = lane & 15, quarter = lane >> 4;

    // stage B1^T: sB[n][k] = (k<64 ? W1l[k][n] : W1r[k-64][n])
    for (int i = t; i < 128 * 128; i += 256) {
        int k = i >> 7, n = i & 127;
        float wv = (k < 64) ? W1l[k * HID + n] : W1r[(k - 64) * HID + n];
        sB[n * LDA + k] = bfbits(wv);
    }
    // stage xb into sA cols 64..127
    for (int i = t; i < 64 * 64; i += 256) {
        int r = i >> 6, c = i & 63;
        int node = min(base + r, N - 1);
        sA[r * LDA + 64 + c] = bfbits(x[(size_t)node * 64 + c]);
    }
    // gather-mean into sA cols 0..63 (wave w -> rows w*16..w*16+15)
    for (int i = 0; i < 16; ++i) {
        int row = w * 16 + i;
        int nodec = min(base + row, N - 1);
        int s0 = row_ptr[nodec], s1 = row_ptr[nodec + 1];
        float a0 = 0.f, a1 = 0.f, a2 = 0.f, a3 = 0.f;
        for (int e = s0; e < s1; e += 16) {
#pragma unroll
            for (int k = 0; k < 4; ++k) {
                int ek = e + quarter + 4 * k;
                bool valid = ek < s1;
                int src = srcs[valid ? ek : 0];
                unsigned u = xf8[(size_t)src * 16 + ql];
                if (valid) {
                    f32x2 lo = __builtin_amdgcn_cvt_pk_f32_fp8((int)u, false);
                    f32x2 hi = __builtin_amdgcn_cvt_pk_f32_fp8((int)u, true);
                    a0 += lo[0]; a1 += lo[1]; a2 += hi[0]; a3 += hi[1];
                }
            }
        }
        a0 += __shfl_xor(a0, 16); a0 += __shfl_xor(a0, 32);
        a1 += __shfl_xor(a1, 16); a1 += __shfl_xor(a1, 32);
        a2 += __shfl_xor(a2, 16); a2 += __shfl_xor(a2, 32);
        a3 += __shfl_xor(a3, 16); a3 += __shfl_xor(a3, 32);
        int deg = s1 - s0;
        float sc = deg > 0 ? 1.f / (float)deg : 0.f;
        if (quarter == 0) {
            uint2 p;
            p.x = bfpack(a0 * sc, a1 * sc);
            p.y = bfpack(a2 * sc, a3 * sc);
            *(uint2*)&sA[row * LDA + 4 * ql] = p;   // 8B-aligned (LDA even)
        }
    }
    __syncthreads();

    // MFMA stage 1: wave w computes rows m0..m0+15 x all 128 cols
    int m0 = w * 16;
    int mr = lane & 15, q = lane >> 4;
    const f32x4 zero = {0.f, 0.f, 0.f, 0.f};
    f32x4 acc[8];
#pragma unroll
    for (int nt = 0; nt < 8; ++nt) acc[nt] = zero;
#pragma unroll
    for (int kt = 0; kt < 4; ++kt) {
        short8 a = *reinterpret_cast<const short8*>(&sA[(m0 + mr) * LDA + kt * 32 + q * 8]);
#pragma unroll
        for (int nt = 0; nt < 8; ++nt) {
            short8 b = *reinterpret_cast<const short8*>(&sB[(nt * 16 + mr) * LDA + kt * 32 + q * 8]);
            acc[nt] = __builtin_amdgcn_mfma_f32_16x16x32_bf16(a, b, acc[nt], 0, 0, 0);
        }
    }
    __syncthreads(); // all stage-1 sB reads done

    // H1 = relu(acc + b1) -> sA (own strip); restage B2^T -> sB
#pragma unroll
    for (int nt = 0; nt < 8; ++nt)
#pragma unroll
        for (int j = 0; j < 4; ++j) {
            int row = m0 + q * 4 + j;
            int col = nt * 16 + mr;
            float v = acc[nt][j] + b1[col];
            sA[row * LDA + col] = bfbits(fmaxf(v, 0.f));
        }
    for (int i = t; i < 128 * 128; i += 256) {
        int c = i >> 7, n = i & 127;
        float wv = (n < 64) ? W2l[c * HID2 + n] : W2r[c * HID2 + (n - 64)];
        sB[n * LDA + c] = bfbits(wv);
    }
    __syncthreads();

    f32x4 acc2[8];
#pragma unroll
    for (int nt = 0; nt < 8; ++nt) acc2[nt] = zero;
#pragma unroll
    for (int kt = 0; kt < 4; ++kt) {
        short8 a = *reinterpret_cast<const short8*>(&sA[(m0 + mr) * LDA + kt * 32 + q * 8]);
#pragma unroll
        for (int nt = 0; nt < 8; ++nt) {
            short8 b = *reinterpret_cast<const short8*>(&sB[(nt * 16 + mr) * LDA + kt * 32 + q * 8]);
            acc2[nt] = __builtin_amdgcn_mfma_f32_16x16x32_bf16(a, b, acc2[nt], 0, 0, 0);
        }
    }
    __syncthreads(); // stage-2 LDS reads done; reuse sA/sB as staging

    unsigned char* sG = (unsigned char*)sA;      // [64][64] fp8
    unsigned short* sS = (unsigned short*)sB;    // [64][64] bf16
#pragma unroll
    for (int nt = 0; nt < 8; ++nt)
#pragma unroll
        for (int j = 0; j < 4; ++j) {
            int row = m0 + q * 4 + j;
            int col = nt * 16 + mr;
            float v = acc2[nt][j];
            if (col < 64) sG[row * 64 + col] = f_to_fp8(v);
            else          sS[row * 64 + (col - 64)] = bfbits(v);
        }
    __syncthreads();
    const unsigned* sGu = (const unsigned*)sG;
    for (int i = t; i < 64 * 16; i += 256) {
        int r = i >> 4, node = base + r;
        if (node < N) G8[(size_t)node * 16 + (i & 15)] = sGu[i];
    }
    const unsigned* sSu = (const unsigned*)sS;
    for (int i = t; i < 64 * 32; i += 256) {
        int r = i >> 5, node = base + r;
        if (node < N) S2u[(size_t)node * 32 + (i & 31)] = sSu[i];
    }
}

// ---------------- k5: gather-mean of G(fp8) + FC + sigmoid ----------------
__global__ __launch_bounds__(256) void agg2fc_kernel(
    const unsigned* __restrict__ G8, const int* __restrict__ row_ptr,
    const int* __restrict__ srcs, const unsigned* __restrict__ S2u,
    const float* __restrict__ b2, const float* __restrict__ Wfc,
    const float* __restrict__ bfc, float* __restrict__ out, int N)
{
    int g = blockIdx.x * 256 + threadIdx.x;
    int node = g >> 6;
    if (node >= N) return;
    int lane = g & 63, ql = lane & 15, quarter = lane >> 4;
    int s0 = row_ptr[node], s1 = row_ptr[node + 1];
    float a0 = 0.f, a1 = 0.f, a2 = 0.f, a3 = 0.f;
    for (int e = s0; e < s1; e += 16) {
#pragma unroll
        for (int k = 0; k < 4; ++k) {
            int ek = e + quarter + 4 * k;
            bool valid = ek < s1;
            int src = srcs[valid ? ek : 0];
            unsigned u = G8[(size_t)src * 16 + ql];
            if (valid) {
                f32x2 lo = __builtin_amdgcn_cvt_pk_f32_fp8((int)u, false);
                f32x2 hi = __builtin_amdgcn_cvt_pk_f32_fp8((int)u, true);
                a0 += lo[0]; a1 += lo[1]; a2 += hi[0]; a3 += hi[1];
            }
        }
    }
    a0 += __shfl_xor(a0, 16); a0 += __shfl_xor(a0, 32);
    a1 += __shfl_xor(a1, 16); a1 += __shfl_xor(a1, 32);
    a2 += __shfl_xor(a2, 16); a2 += __shfl_xor(a2, 32);
    a3 += __shfl_xor(a3, 16); a3 += __shfl_xor(a3, 32);
    int deg = s1 - s0;
    float scale = deg > 0 ? 1.f / (float)deg : 0.f;
    uint2 s2p = ((const uint2*)(S2u + (size_t)node * 32))[ql];
    float4 b4 = ((const float4*)b2)[ql];
    float4 w4 = ((const float4*)Wfc)[ql];
    float z = fmaxf(a0 * scale + bflo(s2p.x) + b4.x, 0.f) * w4.x
            + fmaxf(a1 * scale + bfhi(s2p.x) + b4.y, 0.f) * w4.y
            + fmaxf(a2 * scale + bflo(s2p.y) + b4.z, 0.f) * w4.z
            + fmaxf(a3 * scale + bfhi(s2p.y) + b4.w, 0.f) * w4.w;
    z += __shfl_xor(z, 1); z += __shfl_xor(z, 2);
    z += __shfl_xor(z, 4); z += __shfl_xor(z, 8);
    if (lane == 0) out[node] = 1.f / (1.f + __expf(-(z + bfc[0])));
}

// ---------------- launch ----------------
static inline size_t align_up(size_t v, size_t a) { return (v + a - 1) & ~(a - 1); }

extern "C" void kernel_launch(void* const* d_in, const int* in_sizes, int n_in,
                              void* d_out, int out_size, void* d_ws, size_t ws_size,
                              hipStream_t stream) {
    const float* x   = (const float*)d_in[0];
    const int*   ei  = (const int*)d_in[1];
    const float* W1l = (const float*)d_in[2];
    const float* b1  = (const float*)d_in[3];
    const float* W1r = (const float*)d_in[4];
    const float* W2l = (const float*)d_in[5];
    const float* b2  = (const float*)d_in[6];
    const float* W2r = (const float*)d_in[7];
    const float* Wfc = (const float*)d_in[8];
    const float* bfc = (const float*)d_in[9];
    float* out = (float*)d_out;

    const int N = in_sizes[0] / IN_C;   // 100000
    const int E = in_sizes[1] / 2;      // 1600000
    const int NBUCK = (N + BR - 1) / BR;        // 196
    const int EPB = (E + P1B - 1) / P1B;        // 6250

    char* ws = (char*)d_ws;
    size_t o = 0;
    int* row_ptr  = (int*)(ws + o); o = align_up(o + (size_t)(N + 1) * 4, 256);
    int* srcs     = (int*)(ws + o); o = align_up(o + (size_t)E * 4, 256);
    int* cnt      = (int*)(ws + o); o = align_up(o + (size_t)P1B * 256 * 4, 256);
    int* bb       = (int*)(ws + o); o = align_up(o + 257 * 4, 256);
    // part (E*4 = 6.4 MB) aliases S2u (N*128 B = 12.8 MB): part dead after csr.
    size_t part_off = o;
    size_t sz1 = (size_t)E * 4, sz2 = (size_t)N * 128;
    o = align_up(part_off + (sz1 > sz2 ? sz1 : sz2), 256);
    int* part = (int*)(ws + part_off);
    unsigned* S2u = (unsigned*)(ws + part_off);
    unsigned* xf8 = (unsigned*)(ws + o); o = align_up(o + (size_t)N * 16 * 4, 256);
    unsigned* G8  = (unsigned*)(ws + o); o = align_up(o + (size_t)N * 16 * 4, 256);

    count_kernel<<<P1B, 256, 0, stream>>>(ei, cnt, (const float4*)x, xf8,
                                          N * 16, E, EPB, NBUCK);
    scatter_kernel<<<P1B, 256, 0, stream>>>(ei, cnt, bb, row_ptr, part,
                                            N, E, EPB, NBUCK);
    csr_kernel<<<NBUCK, 256, 0, stream>>>(part, bb, row_ptr, srcs, N);
    aggdense_kernel<<<(N + 63) / 64, 256, 0, stream>>>(
        xf8, row_ptr, srcs, x, W1l, b1, W1r, W2l, W2r, G8, S2u, N);
    int gwb = (N * 64 + 255) / 256;
    agg2fc_kernel<<<gwb, 256, 0, stream>>>(G8, row_ptr, srcs, S2u, b2, Wfc, bfc, out, N);
}

// Round 13
// 297.100 us; speedup vs baseline: 2.7238x; 1.2845x over previous
//
#include <hip/hip_runtime.h>
#include <hip/hip_bf16.h>
#include <math.h>

// FraudGNN on MI355X. 5 kernels:
//   fscatter (LDS-hist + global-atomic slot reservation -> padded buckets,
//             folds x->fp8) | csr (per-bucket local CSR, row2 int2) |
//   agg1 (quarter-wave fp8 gather-mean) | dense MFMA (H1->G fp8, S2 bf16) |
//   agg2fc (fp8 gather + FC + sigmoid).
// Gathers stay standalone at high TLP (R7/R11/R12: any fusion that caps wave
// count starves the latency-bound gather). Aggs ride ~87% of the per-XCD
// L2-miss line-service ceiling; FETCH ~23% above compulsory.

#define IN_C 64
#define HID 128
#define HID2 64
#define LDA 136     // LDS row stride for MFMA tiles
#define NBSHIFT 9   // 512 nodes per bucket
#define BR 512
#define CAP 10240   // padded bucket capacity (mean 8192, sd ~90 -> 22 sigma)
#define P1B 256     // partition chunks (needs NBUCK <= 256: N <= 131072)

typedef short short8 __attribute__((ext_vector_type(8)));
typedef float f32x4 __attribute__((ext_vector_type(4)));
typedef float f32x2 __attribute__((ext_vector_type(2)));

__device__ inline unsigned short bfbits(float f) {
    __hip_bfloat16 h = __float2bfloat16(f);
    return *reinterpret_cast<unsigned short*>(&h);
}
__device__ inline float bflo(unsigned u) { return __uint_as_float(u << 16); }
__device__ inline float bfhi(unsigned u) { return __uint_as_float(u & 0xffff0000u); }
__device__ inline unsigned bfpack(float a, float b) {
    return ((unsigned)bfbits(b) << 16) | (unsigned)bfbits(a);
}
__device__ inline unsigned char f_to_fp8(float v) {
    return (unsigned char)(__builtin_amdgcn_cvt_pk_fp8_f32(v, v, 0, false) & 0xff);
}

// ---------------- k1: fused count+scatter (+ x->fp8) ----------------
// LDS hist of the chunk -> one global atomicAdd per bucket reserves a
// contiguous range in the padded bucket region -> scatter packed records.
__global__ __launch_bounds__(256) void fscatter_kernel(
    const int* __restrict__ ei, int* __restrict__ fill,
    int* __restrict__ part,
    const float4* __restrict__ x4, unsigned* __restrict__ xf8,
    int n4, int E, int EPB, int NBUCK)
{
    __shared__ int hist[256];
    __shared__ int lofs[256];
    int t = threadIdx.x, j = blockIdx.x;
    hist[t] = 0;
    __syncthreads();
    int e0 = j * EPB, e1 = min(e0 + EPB, E);
    for (int e = e0 + t; e < e1; e += 256)
        atomicAdd(&hist[ei[E + e] >> NBSHIFT], 1);
    // folded x -> fp8 conversion (independent work, hides hist latency)
    for (int i = j * 256 + t; i < n4; i += P1B * 256) {
        float4 f = x4[i];
        int lo = __builtin_amdgcn_cvt_pk_fp8_f32(f.x, f.y, 0, false);
        xf8[i] = (unsigned)__builtin_amdgcn_cvt_pk_fp8_f32(f.z, f.w, lo, true);
    }
    __syncthreads();
    if (t < NBUCK) {
        int h = hist[t];
        lofs[t] = (h > 0) ? atomicAdd(&fill[t], h) : 0;
    }
    __syncthreads();
    for (int e = e0 + t; e < e1; e += 256) {
        int s = ei[e], d = ei[E + e];
        int b = d >> NBSHIFT;
        int p = atomicAdd(&lofs[b], 1);
        if (p < CAP) part[(size_t)b * CAP + p] = (s << NBSHIFT) | (d & (BR - 1));
    }
}

// ---------------- k2: per-bucket local CSR ----------------
__global__ __launch_bounds__(256) void csr_kernel(
    const int* __restrict__ part, const int* __restrict__ fill,
    int2* __restrict__ row2, int* __restrict__ srcs, int N)
{
    __shared__ int ncnt[BR];
    __shared__ int nofs[BR];
    __shared__ int nfill[BR];
    __shared__ int wred[4];
    int b = blockIdx.x;
    int t = threadIdx.x, lane = t & 63, w = t >> 6;
    int node0 = b << NBSHIFT;
    int nn = min(BR, N - node0);
    int base = b * CAP;
    int cntb = min(fill[b], CAP);
    ncnt[t] = 0; ncnt[t + 256] = 0;
    __syncthreads();
    for (int i = t; i < cntb; i += 256)
        atomicAdd(&ncnt[part[base + i] & (BR - 1)], 1);
    __syncthreads();
    int c0 = ncnt[2 * t], c1 = ncnt[2 * t + 1];
    int v = c0 + c1;
    int x = v;
    for (int off = 1; off < 64; off <<= 1) {
        int u = __shfl_up(x, off);
        if (lane >= off) x += u;
    }
    if (lane == 63) wred[w] = x;
    __syncthreads();
    int add = 0;
    for (int k = 0; k < w; ++k) add += wred[k];
    int exc = x + add - v;
    nofs[2 * t] = exc;          nofs[2 * t + 1] = exc + c0;
    nfill[2 * t] = exc;         nfill[2 * t + 1] = exc + c0;
    __syncthreads();
    for (int i = t; i < nn; i += 256) {
        int beg = base + nofs[i];
        row2[node0 + i] = make_int2(beg, beg + ncnt[i]);
    }
    for (int i = t; i < cntb; i += 256) {
        int p = part[base + i];
        int pos = atomicAdd(&nfill[p & (BR - 1)], 1);
        srcs[base + pos] = ((unsigned)p) >> NBSHIFT;
    }
}

// ---------------- k3: gather-mean of x(fp8) -> M1 (bf16) ----------------
// Quarter-wave (16 lanes x 4B = 64B = 1 line) per edge; 4 edges per load inst.
__global__ __launch_bounds__(256) void agg1_kernel(
    const unsigned* __restrict__ xf8, const int2* __restrict__ row2,
    const int* __restrict__ srcs, unsigned* __restrict__ M1u, int N)
{
    int g = blockIdx.x * 256 + threadIdx.x;
    int node = g >> 6;
    if (node >= N) return;
    int lane = g & 63, ql = lane & 15, quarter = lane >> 4;
    int2 r = row2[node];
    int s0 = r.x, s1 = r.y;
    float a0 = 0.f, a1 = 0.f, a2 = 0.f, a3 = 0.f;
    for (int e = s0; e < s1; e += 16) {
#pragma unroll
        for (int k = 0; k < 4; ++k) {
            int ek = e + quarter + 4 * k;
            bool valid = ek < s1;
            int src = srcs[valid ? ek : s0];
            unsigned u = xf8[(size_t)src * 16 + ql];
            if (valid) {
                f32x2 lo = __builtin_amdgcn_cvt_pk_f32_fp8((int)u, false);
                f32x2 hi = __builtin_amdgcn_cvt_pk_f32_fp8((int)u, true);
                a0 += lo[0]; a1 += lo[1]; a2 += hi[0]; a3 += hi[1];
            }
        }
    }
    a0 += __shfl_xor(a0, 16); a0 += __shfl_xor(a0, 32);
    a1 += __shfl_xor(a1, 16); a1 += __shfl_xor(a1, 32);
    a2 += __shfl_xor(a2, 16); a2 += __shfl_xor(a2, 32);
    a3 += __shfl_xor(a3, 16); a3 += __shfl_xor(a3, 32);
    int deg = s1 - s0;
    float scale = deg > 0 ? 1.f / (float)deg : 0.f;
    if (quarter == 0) {
        uint2 p;
        p.x = bfpack(a0 * scale, a1 * scale);
        p.y = bfpack(a2 * scale, a3 * scale);
        ((uint2*)M1u)[(size_t)node * 16 + ql] = p;
    }
}

// ---------------- k4: fused dense: H1 -> G (fp8), S2 (bf16) ----------------
__global__ __launch_bounds__(256) void dense_kernel(
    const unsigned short* __restrict__ M1s, const float* __restrict__ x,
    const float* __restrict__ W1l, const float* __restrict__ b1,
    const float* __restrict__ W1r, const float* __restrict__ W2l,
    const float* __restrict__ W2r, unsigned* __restrict__ G8,
    unsigned* __restrict__ S2u, int N)
{
    __shared__ unsigned short sA[128 * LDA];
    __shared__ unsigned short sB[128 * LDA];
    int tid = threadIdx.x;
    int base = blockIdx.x * 128;

    for (int i = tid; i < 128 * 128; i += 256) {
        int k = i >> 7, n = i & 127;
        float wv = (k < 64) ? W1l[k * HID + n] : W1r[(k - 64) * HID + n];
        sB[n * LDA + k] = bfbits(wv);
    }
    for (int i = tid; i < 128 * 64; i += 256) {
        int r = i >> 6, c = i & 63;
        int node = min(base + r, N - 1);
        sA[r * LDA + c] = M1s[(size_t)node * 64 + c];
        sA[r * LDA + 64 + c] = bfbits(x[(size_t)node * 64 + c]);
    }
    __syncthreads();

    int w = tid >> 6, lane = tid & 63;
    int m0 = w * 32;
    int mr = lane & 15, q = lane >> 4;
    const f32x4 zero = {0.f, 0.f, 0.f, 0.f};

    f32x4 acc[2][8];
#pragma unroll
    for (int mt = 0; mt < 2; ++mt)
#pragma unroll
        for (int nt = 0; nt < 8; ++nt) acc[mt][nt] = zero;

#pragma unroll
    for (int kt = 0; kt < 4; ++kt) {
        short8 a0 = *reinterpret_cast<const short8*>(&sA[(m0 + mr) * LDA + kt * 32 + q * 8]);
        short8 a1 = *reinterpret_cast<const short8*>(&sA[(m0 + 16 + mr) * LDA + kt * 32 + q * 8]);
#pragma unroll
        for (int nt = 0; nt < 8; ++nt) {
            short8 b = *reinterpret_cast<const short8*>(&sB[(nt * 16 + mr) * LDA + kt * 32 + q * 8]);
            acc[0][nt] = __builtin_amdgcn_mfma_f32_16x16x32_bf16(a0, b, acc[0][nt], 0, 0, 0);
            acc[1][nt] = __builtin_amdgcn_mfma_f32_16x16x32_bf16(a1, b, acc[1][nt], 0, 0, 0);
        }
    }
    __syncthreads();

#pragma unroll
    for (int mt = 0; mt < 2; ++mt)
#pragma unroll
        for (int nt = 0; nt < 8; ++nt)
#pragma unroll
            for (int j = 0; j < 4; ++j) {
                int row = m0 + mt * 16 + q * 4 + j;
                int col = nt * 16 + mr;
                float v = acc[mt][nt][j] + b1[col];
                sA[row * LDA + col] = bfbits(fmaxf(v, 0.f));
            }
    for (int i = tid; i < 128 * 128; i += 256) {
        int c = i >> 7, n = i & 127;
        float wv = (n < 64) ? W2l[c * HID2 + n] : W2r[c * HID2 + (n - 64)];
        sB[n * LDA + c] = bfbits(wv);
    }
    __syncthreads();

    f32x4 acc2[2][8];
#pragma unroll
    for (int mt = 0; mt < 2; ++mt)
#pragma unroll
        for (int nt = 0; nt < 8; ++nt) acc2[mt][nt] = zero;

#pragma unroll
    for (int kt = 0; kt < 4; ++kt) {
        short8 a0 = *reinterpret_cast<const short8*>(&sA[(m0 + mr) * LDA + kt * 32 + q * 8]);
        short8 a1 = *reinterpret_cast<const short8*>(&sA[(m0 + 16 + mr) * LDA + kt * 32 + q * 8]);
#pragma unroll
        for (int nt = 0; nt < 8; ++nt) {
            short8 b = *reinterpret_cast<const short8*>(&sB[(nt * 16 + mr) * LDA + kt * 32 + q * 8]);
            acc2[0][nt] = __builtin_amdgcn_mfma_f32_16x16x32_bf16(a0, b, acc2[0][nt], 0, 0, 0);
            acc2[1][nt] = __builtin_amdgcn_mfma_f32_16x16x32_bf16(a1, b, acc2[1][nt], 0, 0, 0);
        }
    }
    __syncthreads(); // stage-2 LDS reads done; reuse sA/sB as output staging

    unsigned char* sG = (unsigned char*)sA;     // [128][64] fp8
    unsigned short* sS = (unsigned short*)sB;   // [128][64] bf16
#pragma unroll
    for (int mt = 0; mt < 2; ++mt)
#pragma unroll
        for (int nt = 0; nt < 8; ++nt)
#pragma unroll
            for (int j = 0; j < 4; ++j) {
                int row = m0 + mt * 16 + q * 4 + j;
                int col = nt * 16 + mr;
                float v = acc2[mt][nt][j];
                if (col < 64) sG[row * 64 + col] = f_to_fp8(v);
                else          sS[row * 64 + (col - 64)] = bfbits(v);
            }
    __syncthreads();
    const unsigned* sGu = (const unsigned*)sG;
    for (int i = tid; i < 128 * 16; i += 256) {
        int r = i >> 4, node = base + r;
        if (node < N) G8[(size_t)node * 16 + (i & 15)] = sGu[i];
    }
    const unsigned* sSu = (const unsigned*)sS;
    for (int i = tid; i < 128 * 32; i += 256) {
        int r = i >> 5, node = base + r;
        if (node < N) S2u[(size_t)node * 32 + (i & 31)] = sSu[i];
    }
}

// ---------------- k5: gather-mean of G(fp8) + FC + sigmoid ----------------
__global__ __launch_bounds__(256) void agg2fc_kernel(
    const unsigned* __restrict__ G8, const int2* __restrict__ row2,
    const int* __restrict__ srcs, const unsigned* __restrict__ S2u,
    const float* __restrict__ b2, const float* __restrict__ Wfc,
    const float* __restrict__ bfc, float* __restrict__ out, int N)
{
    int g = blockIdx.x * 256 + threadIdx.x;
    int node = g >> 6;
    if (node >= N) return;
    int lane = g & 63, ql = lane & 15, quarter = lane >> 4;
    int2 r = row2[node];
    int s0 = r.x, s1 = r.y;
    float a0 = 0.f, a1 = 0.f, a2 = 0.f, a3 = 0.f;
    for (int e = s0; e < s1; e += 16) {
#pragma unroll
        for (int k = 0; k < 4; ++k) {
            int ek = e + quarter + 4 * k;
            bool valid = ek < s1;
            int src = srcs[valid ? ek : s0];
            unsigned u = G8[(size_t)src * 16 + ql];
            if (valid) {
                f32x2 lo = __builtin_amdgcn_cvt_pk_f32_fp8((int)u, false);
                f32x2 hi = __builtin_amdgcn_cvt_pk_f32_fp8((int)u, true);
                a0 += lo[0]; a1 += lo[1]; a2 += hi[0]; a3 += hi[1];
            }
        }
    }
    a0 += __shfl_xor(a0, 16); a0 += __shfl_xor(a0, 32);
    a1 += __shfl_xor(a1, 16); a1 += __shfl_xor(a1, 32);
    a2 += __shfl_xor(a2, 16); a2 += __shfl_xor(a2, 32);
    a3 += __shfl_xor(a3, 16); a3 += __shfl_xor(a3, 32);
    int deg = s1 - s0;
    float scale = deg > 0 ? 1.f / (float)deg : 0.f;
    uint2 s2p = ((const uint2*)(S2u + (size_t)node * 32))[ql];
    float4 b4 = ((const float4*)b2)[ql];
    float4 w4 = ((const float4*)Wfc)[ql];
    float z = fmaxf(a0 * scale + bflo(s2p.x) + b4.x, 0.f) * w4.x
            + fmaxf(a1 * scale + bfhi(s2p.x) + b4.y, 0.f) * w4.y
            + fmaxf(a2 * scale + bflo(s2p.y) + b4.z, 0.f) * w4.z
            + fmaxf(a3 * scale + bfhi(s2p.y) + b4.w, 0.f) * w4.w;
    z += __shfl_xor(z, 1); z += __shfl_xor(z, 2);
    z += __shfl_xor(z, 4); z += __shfl_xor(z, 8);
    if (lane == 0) out[node] = 1.f / (1.f + __expf(-(z + bfc[0])));
}

// ---------------- launch ----------------
static inline size_t align_up(size_t v, size_t a) { return (v + a - 1) & ~(a - 1); }

extern "C" void kernel_launch(void* const* d_in, const int* in_sizes, int n_in,
                              void* d_out, int out_size, void* d_ws, size_t ws_size,
                              hipStream_t stream) {
    const float* x   = (const float*)d_in[0];
    const int*   ei  = (const int*)d_in[1];
    const float* W1l = (const float*)d_in[2];
    const float* b1  = (const float*)d_in[3];
    const float* W1r = (const float*)d_in[4];
    const float* W2l = (const float*)d_in[5];
    const float* b2  = (const float*)d_in[6];
    const float* W2r = (const float*)d_in[7];
    const float* Wfc = (const float*)d_in[8];
    const float* bfc = (const float*)d_in[9];
    float* out = (float*)d_out;

    const int N = in_sizes[0] / IN_C;   // 100000
    const int E = in_sizes[1] / 2;      // 1600000
    const int NBUCK = (N + BR - 1) / BR;        // 196
    const int EPB = (E + P1B - 1) / P1B;        // 6250

    char* ws = (char*)d_ws;
    size_t o = 0;
    int2* row2   = (int2*)(ws + o); o = align_up(o + (size_t)N * 8, 256);
    int* srcs    = (int*)(ws + o); o = align_up(o + (size_t)NBUCK * CAP * 4, 256);
    int* fill    = (int*)(ws + o); o = align_up(o + (size_t)(NBUCK + 1) * 4, 256);
    // part (NBUCK*CAP*4 = 8.0 MB) aliases S2u (N*128 B = 12.8 MB): part dead
    // after csr; S2u written in dense (after csr).
    size_t part_off = o;
    size_t sz1 = (size_t)NBUCK * CAP * 4, sz2 = (size_t)N * 128;
    o = align_up(part_off + (sz1 > sz2 ? sz1 : sz2), 256);
    int* part = (int*)(ws + part_off);
    unsigned* S2u = (unsigned*)(ws + part_off);
    unsigned* xf8 = (unsigned*)(ws + o); o = align_up(o + (size_t)N * 16 * 4, 256);
    unsigned* M1u = (unsigned*)(ws + o); o = align_up(o + (size_t)N * 32 * 4, 256);
    unsigned* G8  = (unsigned*)(ws + o); o = align_up(o + (size_t)N * 16 * 4, 256);

    hipMemsetAsync(fill, 0, (size_t)(NBUCK + 1) * 4, stream);
    fscatter_kernel<<<P1B, 256, 0, stream>>>(ei, fill, part, (const float4*)x,
                                             xf8, N * 16, E, EPB, NBUCK);
    csr_kernel<<<NBUCK, 256, 0, stream>>>(part, fill, row2, srcs, N);
    int gwb = (N * 64 + 255) / 256;
    agg1_kernel<<<gwb, 256, 0, stream>>>(xf8, row2, srcs, M1u, N);
    dense_kernel<<<(N + 127) / 128, 256, 0, stream>>>(
        (const unsigned short*)M1u, x, W1l, b1, W1r, W2l, W2r, G8, S2u, N);
    agg2fc_kernel<<<gwb, 256, 0, stream>>>(G8, row2, srcs, S2u, b2, Wfc, bfc, out, N);
}